// Round 6
// baseline (410.338 us; speedup 1.0000x reference)
//
#include <hip/hip_runtime.h>
#include <math.h>

#define B_SZ   32
#define C_DIM  384
#define H_IN   28
#define W_IN   28
#define TQ     785   // 1 + 28*28
#define TKV    197   // 1 + 14*14
#define NH     6
#define HD     64
#define SCALE_F 0.05103103630798287f       // 384^-0.5
#define SCALE_L2E (0.05103103630798287f * 1.4426950408889634f)  // fold log2(e)
#define BN_EPS_F 1e-5f

#define QROWS    25120        // B_SZ*TQ
#define KVROWS   6304         // B_SZ*TKV
#define QROWS_P  25344        // workspace padding (>= 393*64)
#define KVROWS_P 6528         // workspace padding (>= 99*64)
#define WELEM    147456       // 384*384
#define VT_LD    208          // V^T key stride (16B-aligned rows, >= 197)

#define QT64     393          // 64-row M-tiles for Q rows (25120 -> 25152)
#define KVT64    99           // 64-row M-tiles for K/V rows (6304 -> 6336)

typedef _Float16 f16;
typedef f16  f16x8 __attribute__((ext_vector_type(8)));
typedef f16  f16x4 __attribute__((ext_vector_type(4)));
typedef float f32x4 __attribute__((ext_vector_type(4)));

__device__ __forceinline__ void split16(float v, f16& h, f16& l) {
    h = (f16)v;
    l = (f16)(v - (float)h);
}

// async global->LDS DMA, 16 B per lane (used by conv + attn staging only).
__device__ __forceinline__ void cp16(void* lds, const void* g) {
    __builtin_amdgcn_global_load_lds(
        (const __attribute__((address_space(1))) unsigned int*)g,
        (__attribute__((address_space(3))) unsigned int*)lds, 16, 0, 0);
}

// ---------------- prep: weight decompose (+scale fold into w_q) + conv/BN fold --
__global__ __launch_bounds__(256) void prep_kernel(
    const float* __restrict__ wq, const float* __restrict__ wk,
    const float* __restrict__ wv, const float* __restrict__ wp,
    const float* __restrict__ conv_w,
    const float* __restrict__ gamma, const float* __restrict__ beta,
    const float* __restrict__ mean, const float* __restrict__ var,
    f16* __restrict__ Wh, f16* __restrict__ Wl,
    float* __restrict__ wAll)
{
    int idx = blockIdx.x * 256 + threadIdx.x;
    if (idx < 4 * WELEM) {
        int which = idx / WELEM, rem = idx - which * WELEM;
        const float* s = (which == 0) ? wq : (which == 1) ? wk : (which == 2) ? wv : wp;
        float v = s[rem];
        if (which == 0) v *= SCALE_L2E;   // QK^T logits in log2 domain
        f16 h, l;
        split16(v, h, l);
        Wh[idx] = h; Wl[idx] = l;
    } else if (idx < 4 * WELEM + 3 * C_DIM) {
        int k = idx - 4 * WELEM;
        int cv = k / C_DIM, c = k - cv * C_DIM;
        float inv = gamma[k] * rsqrtf(var[k] + BN_EPS_F);
#pragma unroll
        for (int t = 0; t < 9; ++t)
            wAll[cv * 3840 + t * C_DIM + c] = conv_w[(size_t)cv * C_DIM * 9 + c * 9 + t] * inv;
        wAll[cv * 3840 + 9 * C_DIM + c] = beta[k] - mean[k] * inv;
    }
}

// ---------------- fused depthwise conv (Q stride1 + K/V stride2) + cls row -----
__global__ __launch_bounds__(256) void fused_conv_kernel(
    const float* __restrict__ x,
    const float* __restrict__ wAll,
    f16* __restrict__ qh, f16* __restrict__ ql,
    f16* __restrict__ kh, f16* __restrict__ kl,
    f16* __restrict__ vh, f16* __restrict__ vl)
{
    __shared__ float sW[3 * 3840];
    int tid = threadIdx.x;
    int oi = blockIdx.x, b = blockIdx.y;

    if (oi == H_IN) {                 // cls-token path
        if (tid < 96) {
            int c = tid * 4;
            float4 v = *(const float4*)&x[(size_t)b * TQ * C_DIM + c];
            float a[4] = {v.x, v.y, v.z, v.w};
            f16x4 hv, lv;
#pragma unroll
            for (int u = 0; u < 4; ++u) { f16 h, l; split16(a[u], h, l); hv[u] = h; lv[u] = l; }
            size_t oq = (size_t)b * TQ * C_DIM + c;
            size_t okv = (size_t)b * TKV * C_DIM + c;
            *(f16x4*)&qh[oq] = hv;  *(f16x4*)&ql[oq] = lv;
            *(f16x4*)&kh[okv] = hv; *(f16x4*)&kl[okv] = lv;
            *(f16x4*)&vh[okv] = hv; *(f16x4*)&vl[okv] = lv;
        }
        return;
    }

#pragma unroll
    for (int i = 0; i < 12; ++i) {
        int idx = tid + 256 * i;
        if (idx < 2880) cp16(&sW[idx * 4], &wAll[idx * 4]);
    }
    __syncthreads();

    const size_t xb = (size_t)b * TQ * C_DIM + C_DIM;
    bool oi_even = (oi & 1) == 0;

    for (int it = 0; it < 11; ++it) {
        int idx = tid + 256 * it;
        if (idx >= 28 * 96) break;
        int oj = idx / 96, cg = idx - oj * 96;
        int c = cg * 4;

        float4 xv[9];
#pragma unroll
        for (int di = 0; di < 3; ++di) {
            int ii = oi + di - 1;
            bool rok = (ii >= 0) && (ii < H_IN);
#pragma unroll
            for (int dj = 0; dj < 3; ++dj) {
                int jj = oj + dj - 1;
                bool ok = rok && (jj >= 0) && (jj < W_IN);
                xv[di * 3 + dj] = ok ? *(const float4*)&x[xb + ((size_t)ii * W_IN + jj) * C_DIM + c]
                                     : make_float4(0.f, 0.f, 0.f, 0.f);
            }
        }

        {
            float4 acc = *(const float4*)&sW[0 * 3840 + 9 * C_DIM + c];
#pragma unroll
            for (int t = 0; t < 9; ++t) {
                float4 w4 = *(const float4*)&sW[0 * 3840 + t * C_DIM + c];
                acc.x += w4.x * xv[t].x; acc.y += w4.y * xv[t].y;
                acc.z += w4.z * xv[t].z; acc.w += w4.w * xv[t].w;
            }
            f16x4 hv, lv;
            float a[4] = {acc.x, acc.y, acc.z, acc.w};
#pragma unroll
            for (int u = 0; u < 4; ++u) { f16 h, l; split16(a[u], h, l); hv[u] = h; lv[u] = l; }
            size_t off = ((size_t)b * TQ + 1 + oi * W_IN + oj) * C_DIM + c;
            *(f16x4*)&qh[off] = hv;
            *(f16x4*)&ql[off] = lv;
        }

        if (oi_even && ((oj & 1) == 0)) {
            int p = (oi >> 1) * 14 + (oj >> 1);
            size_t off = ((size_t)b * TKV + 1 + p) * C_DIM + c;
#pragma unroll
            for (int cv = 1; cv <= 2; ++cv) {
                float4 acc = *(const float4*)&sW[cv * 3840 + 9 * C_DIM + c];
#pragma unroll
                for (int t = 0; t < 9; ++t) {
                    float4 w4 = *(const float4*)&sW[cv * 3840 + t * C_DIM + c];
                    acc.x += w4.x * xv[t].x; acc.y += w4.y * xv[t].y;
                    acc.z += w4.z * xv[t].z; acc.w += w4.w * xv[t].w;
                }
                f16x4 hv, lv;
                float a[4] = {acc.x, acc.y, acc.z, acc.w};
#pragma unroll
                for (int u = 0; u < 4; ++u) { f16 h, l; split16(a[u], h, l); hv[u] = h; lv[u] = l; }
                if (cv == 1) { *(f16x4*)&kh[off] = hv; *(f16x4*)&kl[off] = lv; }
                else         { *(f16x4*)&vh[off] = hv; *(f16x4*)&vl[off] = lv; }
            }
        }
    }
}

// ---------------- split-f16 MFMA GEMM body v6: pure-register, no LDS ----------
// Theory test: 5 rounds of LDS-DMA schedules all pinned at ~72-101 us while the
// global_load_lds path delivered only ~11 B/cyc/CU (m97 proves 22). Operands
// are cache-resident (B: 576 KB -> L2; A: 59 MB unique -> L3, read ONCE at
// BN=384). So stream BOTH operands global->VGPR: no __shared__, no barriers,
// no waitcnt, no DMA engine. 512 thr / 8 waves, tile 64x384, wave 64x48,
// acc[4][3]=48 VGPR. K-loop fully unrolled: 14 fixed base addrs + imm offsets
// (kk*64 <= 704 < 4096) -> zero address math and zero sync in the loop; TLP
// (8 waves) + compiler pipelining hide the (L2/L3-hit) load latency.
// A-access/wave = 16 rows x 64 B contiguous (64-B segments, row stride 768 B).
// Per-lane bytes and MFMA order identical to v5 -> numerics bit-identical.
__device__ __forceinline__ void gemm_body(
    const f16* __restrict__ Ah, const f16* __restrict__ Al,
    const f16* __restrict__ Wh, const f16* __restrict__ Wl,
    const float* __restrict__ bias,
    float* __restrict__ Cf, f16* __restrict__ Coh, f16* __restrict__ Col,
    int M, int mode, int m0)
{
    const int t = threadIdx.x;
    const int wv = t >> 6, lane = t & 63;
    const int wc = wv * 48;           // wave col offset (8 x 48 = 384)
    const int lrow = lane & 15, quad = lane >> 4;

    // MFMA fragment source addresses (per-lane):
    //   A: row = m0 + i*16 + lrow, k = kk*32 + quad*8
    //   B: row = wc + j*16 + lrow, k = kk*32 + quad*8
    const f16* pAh = Ah + (size_t)(m0 + lrow) * 384 + quad * 8;
    const f16* pAl = Al + (size_t)(m0 + lrow) * 384 + quad * 8;
    const f16* pBh = Wh + (size_t)(wc + lrow) * 384 + quad * 8;
    const f16* pBl = Wl + (size_t)(wc + lrow) * 384 + quad * 8;

    f32x4 acc[4][3];
#pragma unroll
    for (int i = 0; i < 4; ++i)
#pragma unroll
        for (int j = 0; j < 3; ++j)
            acc[i][j] = (f32x4){0.f, 0.f, 0.f, 0.f};

#pragma unroll
    for (int kk = 0; kk < 12; ++kk) {
        const int ko = kk * 32;       // compile-time under full unroll
        f16x8 ah[4], al[4], bh[3], bl[3];
#pragma unroll
        for (int i = 0; i < 4; ++i) {
            ah[i] = *(const f16x8*)(pAh + (size_t)i * 16 * 384 + ko);
            al[i] = *(const f16x8*)(pAl + (size_t)i * 16 * 384 + ko);
        }
#pragma unroll
        for (int j = 0; j < 3; ++j) {
            bh[j] = *(const f16x8*)(pBh + (size_t)j * 16 * 384 + ko);
            bl[j] = *(const f16x8*)(pBl + (size_t)j * 16 * 384 + ko);
        }
#pragma unroll
        for (int i = 0; i < 4; ++i)
#pragma unroll
            for (int j = 0; j < 3; ++j) {
                acc[i][j] = __builtin_amdgcn_mfma_f32_16x16x32_f16(ah[i], bh[j], acc[i][j], 0, 0, 0);
                acc[i][j] = __builtin_amdgcn_mfma_f32_16x16x32_f16(ah[i], bl[j], acc[i][j], 0, 0, 0);
                acc[i][j] = __builtin_amdgcn_mfma_f32_16x16x32_f16(al[i], bh[j], acc[i][j], 0, 0, 0);
            }
    }

    // epilogue: C/D layout col=lane&15, row=quad*4+reg
#pragma unroll
    for (int i = 0; i < 4; ++i) {
        int grow0 = m0 + i * 16 + quad * 4;
#pragma unroll
        for (int j = 0; j < 3; ++j) {
            int gcol = wc + j * 16 + lrow;
            float bb = (bias && mode == 0) ? bias[gcol] : 0.f;
#pragma unroll
            for (int r = 0; r < 4; ++r) {
                int grow = grow0 + r;
                if (grow >= M) continue;
                float v = acc[i][j][r] + bb;
                if (mode == 0) {
                    Cf[(size_t)grow * 384 + gcol] = v;
                } else if (mode == 1) {
                    f16 h, l;
                    split16(v, h, l);
                    Coh[(size_t)grow * 384 + gcol] = h;
                    Col[(size_t)grow * 384 + gcol] = l;
                } else {
                    int bb2 = grow / TKV;
                    int key = grow - bb2 * TKV;
                    size_t off = (size_t)bb2 * 384 * VT_LD + (size_t)gcol * VT_LD + key;
                    f16 h, l;
                    split16(v, h, l);
                    Coh[off] = h;
                    Col[off] = l;
                }
            }
        }
    }
}

// Q/K/V projections. y in [0,393) Q, [393,492) K, [492,591) V.
__global__ __launch_bounds__(512) void qkv_proj_kernel(
    const f16* __restrict__ qh, const f16* __restrict__ ql,
    const f16* __restrict__ kh, const f16* __restrict__ kl,
    const f16* __restrict__ vh, const f16* __restrict__ vl,
    const f16* __restrict__ Wh, const f16* __restrict__ Wl,
    f16* __restrict__ Qph, f16* __restrict__ Qpl,
    f16* __restrict__ Kph, f16* __restrict__ Kpl,
    f16* __restrict__ VTh, f16* __restrict__ VTl,
    int yMax)
{
    int y = blockIdx.x;
    if (y >= yMax) return;
    if (y < QT64)
        gemm_body(qh, ql, Wh, Wl, nullptr, nullptr, Qph, Qpl, QROWS, 1, y * 64);
    else if (y < QT64 + KVT64)
        gemm_body(kh, kl, Wh + WELEM, Wl + WELEM, nullptr, nullptr, Kph, Kpl,
                  KVROWS, 1, (y - QT64) * 64);
    else
        gemm_body(vh, vl, Wh + 2 * WELEM, Wl + 2 * WELEM, nullptr, nullptr, VTh, VTl,
                  KVROWS, 2, (y - QT64 - KVT64) * 64);
}

// fallback V projection (aliased-VT workspace layout)
__global__ __launch_bounds__(512) void v_proj_kernel(
    const f16* __restrict__ vh, const f16* __restrict__ vl,
    const f16* __restrict__ Wh, const f16* __restrict__ Wl,
    f16* __restrict__ VTh, f16* __restrict__ VTl)
{
    int y = blockIdx.x;
    if (y >= KVT64) return;
    gemm_body(vh, vl, Wh, Wl, nullptr, nullptr, VTh, VTl, KVROWS, 2, y * 64);
}

__global__ __launch_bounds__(512) void out_proj_kernel(
    const f16* __restrict__ Ah, const f16* __restrict__ Al,
    const f16* __restrict__ Wh, const f16* __restrict__ Wl,
    const float* __restrict__ bias, float* __restrict__ Cf)
{
    int y = blockIdx.x;
    if (y >= QT64) return;
    gemm_body(Ah, Al, Wh, Wl, bias, Cf, nullptr, nullptr, QROWS, 0, y * 64);
}

// ---------------- MFMA attention v4: single-pass softmax + hidden DMA ----------
// (measured-best attn: R0 = 292.8 us total with v4 vs 303 us with v5)
__global__ __launch_bounds__(256) void attn_mfma4(
    const f16* __restrict__ Qh, const f16* __restrict__ Ql,
    const f16* __restrict__ Kh, const f16* __restrict__ Kl,
    const f16* __restrict__ VTh, const f16* __restrict__ VTl,
    f16* __restrict__ Oh, f16* __restrict__ Ol)
{
    __shared__ f16 sQh[2][64][32];
    __shared__ f16 sQl[2][64][32];
    __shared__ f16 sKh[2][64][32];
    __shared__ f16 sKl[2][64][32];
    __shared__ float sPs[64][68];

    int t = threadIdx.x;
    int wv = t >> 6, lane = t & 63;
    int c = lane & 15, quad = lane >> 4;
    int wq0 = wv * 16;
    int h = blockIdx.y, b = blockIdx.z;
    int q0 = blockIdx.x * 64;

    const size_t qbase  = (size_t)b * TQ * C_DIM + h * HD;
    const size_t kbase  = (size_t)b * TKV * C_DIM + h * HD;
    const size_t vtbase = (size_t)b * 384 * VT_LD + (size_t)h * HD * VT_LD;

#pragma unroll
    for (int i = 0; i < 2; ++i) {
        int idx = t + 256 * i;
        int ks = idx >> 8, row = (idx >> 2) & 63, sg = (idx & 3) * 8;
        cp16(&sQh[ks][row][sg], &Qh[qbase + (size_t)(q0 + row) * C_DIM + ks * 32 + sg]);
        cp16(&sQl[ks][row][sg], &Ql[qbase + (size_t)(q0 + row) * C_DIM + ks * 32 + sg]);
    }

    f32x4 s[4][4];
#pragma unroll
    for (int kt = 0; kt < 4; ++kt)
#pragma unroll
        for (int j = 0; j < 4; ++j)
            s[kt][j] = (f32x4){0.f, 0.f, 0.f, 0.f};

#pragma unroll
    for (int kt = 0; kt < 4; ++kt) {
        if (kt) __syncthreads();
#pragma unroll
        for (int i = 0; i < 2; ++i) {
            int idx = t + 256 * i;
            int ks = idx >> 8, row = (idx >> 2) & 63, sg = (idx & 3) * 8;
            cp16(&sKh[ks][row][sg], &Kh[kbase + (size_t)(kt * 64 + row) * C_DIM + ks * 32 + sg]);
            cp16(&sKl[ks][row][sg], &Kl[kbase + (size_t)(kt * 64 + row) * C_DIM + ks * 32 + sg]);
        }
        __syncthreads();

#pragma unroll
        for (int ks = 0; ks < 2; ++ks) {
            f16x8 qh8 = *(const f16x8*)&sQh[ks][wq0 + c][quad * 8];
            f16x8 ql8 = *(const f16x8*)&sQl[ks][wq0 + c][quad * 8];
#pragma unroll
            for (int j = 0; j < 4; ++j) {
                f16x8 kh8 = *(const f16x8*)&sKh[ks][j * 16 + c][quad * 8];
                f16x8 kl8 = *(const f16x8*)&sKl[ks][j * 16 + c][quad * 8];
                s[kt][j] = __builtin_amdgcn_mfma_f32_16x16x32_f16(qh8, kh8, s[kt][j], 0, 0, 0);
                s[kt][j] = __builtin_amdgcn_mfma_f32_16x16x32_f16(qh8, kl8, s[kt][j], 0, 0, 0);
                s[kt][j] = __builtin_amdgcn_mfma_f32_16x16x32_f16(ql8, kh8, s[kt][j], 0, 0, 0);
            }
        }
    }

    __syncthreads();                   // all S frag reads done: K panels free

    // VT tile 0 DMA rides under the softmax VALU
#pragma unroll
    for (int i = 0; i < 2; ++i) {
        int idx = t + 256 * i;
        int ks = idx >> 8, row = (idx >> 2) & 63, sg = (idx & 3) * 8;
        cp16(&sKh[ks][row][sg], &VTh[vtbase + (size_t)row * VT_LD + ks * 32 + sg]);
        cp16(&sKl[ks][row][sg], &VTl[vtbase + (size_t)row * VT_LD + ks * 32 + sg]);
    }

#pragma unroll
    for (int r = 0; r < 4; ++r) {
        s[3][0][r] = (c < 5) ? s[3][0][r] : -1e30f;
        s[3][1][r] = -1e30f;
        s[3][2][r] = -1e30f;
        s[3][3][r] = -1e30f;
    }

    float inv_r[4];
#pragma unroll
    for (int r = 0; r < 4; ++r) {
        float mx = -1e30f;
#pragma unroll
        for (int kt = 0; kt < 4; ++kt)
#pragma unroll
            for (int j = 0; j < 4; ++j)
                mx = fmaxf(mx, s[kt][j][r]);
        mx = fmaxf(mx, __shfl_xor(mx, 1));
        mx = fmaxf(mx, __shfl_xor(mx, 2));
        mx = fmaxf(mx, __shfl_xor(mx, 4));
        mx = fmaxf(mx, __shfl_xor(mx, 8));
        float sum = 0.f;
#pragma unroll
        for (int kt = 0; kt < 4; ++kt)
#pragma unroll
            for (int j = 0; j < 4; ++j) {
                float pv = exp2f(s[kt][j][r] - mx);
                s[kt][j][r] = pv;
                sum += pv;
            }
        sum += __shfl_xor(sum, 1);
        sum += __shfl_xor(sum, 2);
        sum += __shfl_xor(sum, 4);
        sum += __shfl_xor(sum, 8);
        inv_r[r] = 1.f / sum;
    }

    f32x4 o[4];
#pragma unroll
    for (int j = 0; j < 4; ++j) o[j] = (f32x4){0.f, 0.f, 0.f, 0.f};

#pragma unroll
    for (int vt = 0; vt < 4; ++vt) {
#pragma unroll
        for (int r = 0; r < 4; ++r)
#pragma unroll
            for (int j = 0; j < 4; ++j)
                sPs[wq0 + quad * 4 + r][j * 16 + c] = s[vt][j][r];

        __syncthreads();               // drains DMA(vt); sPs visible

#pragma unroll
        for (int ks = 0; ks < 2; ++ks) {
            float4 p0 = *(const float4*)&sPs[wq0 + c][ks * 32 + quad * 8];
            float4 p1 = *(const float4*)&sPs[wq0 + c][ks * 32 + quad * 8 + 4];
            float pf[8] = {p0.x, p0.y, p0.z, p0.w, p1.x, p1.y, p1.z, p1.w};
            f16x8 ph8, pl8;
#pragma unroll
            for (int ii = 0; ii < 8; ++ii) {
                f16 hh, ll;
                split16(pf[ii], hh, ll);
                ph8[ii] = hh; pl8[ii] = ll;
            }
#pragma unroll
            for (int j = 0; j < 4; ++j) {
                f16x8 vh8 = *(const f16x8*)&sKh[ks][j * 16 + c][quad * 8];
                f16x8 vl8 = *(const f16x8*)&sKl[ks][j * 16 + c][quad * 8];
                o[j] = __builtin_amdgcn_mfma_f32_16x16x32_f16(ph8, vh8, o[j], 0, 0, 0);
                o[j] = __builtin_amdgcn_mfma_f32_16x16x32_f16(ph8, vl8, o[j], 0, 0, 0);
                o[j] = __builtin_amdgcn_mfma_f32_16x16x32_f16(pl8, vh8, o[j], 0, 0, 0);
            }
        }

        if (vt < 3) {
            __syncthreads();
#pragma unroll
            for (int i = 0; i < 2; ++i) {
                int idx = t + 256 * i;
                int ks = idx >> 8, row = (idx >> 2) & 63, sg = (idx & 3) * 8;
                cp16(&sKh[ks][row][sg],
                     &VTh[vtbase + (size_t)row * VT_LD + (vt + 1) * 64 + ks * 32 + sg]);
                cp16(&sKl[ks][row][sg],
                     &VTl[vtbase + (size_t)row * VT_LD + (vt + 1) * 64 + ks * 32 + sg]);
            }
        }
    }

#pragma unroll
    for (int r = 0; r < 4; ++r) {
        int gq = q0 + wq0 + quad * 4 + r;
        if (gq >= TQ) continue;
        float inv = inv_r[r];
#pragma unroll
        for (int j = 0; j < 4; ++j) {
            float v = o[j][r] * inv;
            f16 hh, ll;
            split16(v, hh, ll);
            size_t off = (size_t)(b * TQ + gq) * C_DIM + h * HD + j * 16 + c;
            Oh[off] = hh;
            Ol[off] = ll;
        }
    }
}

extern "C" void kernel_launch(void* const* d_in, const int* in_sizes, int n_in,
                              void* d_out, int out_size, void* d_ws, size_t ws_size,
                              hipStream_t stream) {
    const float* x       = (const float*)d_in[0];
    const float* conv_w  = (const float*)d_in[1];
    const float* bn_g    = (const float*)d_in[2];
    const float* bn_b    = (const float*)d_in[3];
    const float* bn_m    = (const float*)d_in[4];
    const float* bn_v    = (const float*)d_in[5];
    const float* w_q     = (const float*)d_in[6];
    const float* w_k     = (const float*)d_in[7];
    const float* w_v     = (const float*)d_in[8];
    const float* w_proj  = (const float*)d_in[9];
    const float* b_proj  = (const float*)d_in[10];
    float* out = (float*)d_out;

    const size_t QSZ   = (size_t)QROWS_P * 384 * sizeof(f16);
    const size_t KVSZ  = (size_t)KVROWS_P * 384 * sizeof(f16);
    const size_t WSZ   = 4 * (size_t)WELEM * sizeof(f16);
    const size_t VTSZ  = (size_t)B_SZ * 384 * VT_LD * sizeof(f16);
    const size_t WALLS = 3 * 3840 * sizeof(float);

    char* p = (char*)d_ws;
    f16* qh  = (f16*)p; p += QSZ;
    f16* ql  = (f16*)p; p += QSZ;
    f16* vh  = (f16*)p; p += KVSZ;
    f16* vl  = (f16*)p; p += KVSZ;
    f16* kh  = (f16*)p; p += KVSZ;
    f16* kl  = (f16*)p; p += KVSZ;
    f16* Wh  = (f16*)p; p += WSZ;
    f16* Wl  = (f16*)p; p += WSZ;
    f16* Qph = (f16*)p; p += QSZ;
    f16* Qpl = (f16*)p; p += QSZ;
    f16* Kph = (f16*)p; p += KVSZ;
    f16* Kpl = (f16*)p; p += KVSZ;
    float* wAll = (float*)p; p += WALLS;

    size_t used = (size_t)(p - (char*)d_ws);
    bool sepVT = (ws_size >= used + 2 * VTSZ);
    f16 *VTh, *VTl;
    if (sepVT) {
        VTh = (f16*)p;
        VTl = VTh + (size_t)B_SZ * 384 * VT_LD;
    } else {
        VTh = kh;
        VTl = VTh + (size_t)B_SZ * 384 * VT_LD;
    }
    f16* oh = qh;
    f16* ol = ql;

    // 1) prep
    {
        int total = 4 * WELEM + 3 * C_DIM;
        prep_kernel<<<(total + 255) / 256, 256, 0, stream>>>(
            w_q, w_k, w_v, w_proj, conv_w, bn_g, bn_b, bn_m, bn_v, Wh, Wl, wAll);
    }

    // 2) fused conv (Q + K + V + cls)
    {
        dim3 gc(H_IN + 1, B_SZ);
        fused_conv_kernel<<<gc, 256, 0, stream>>>(x, wAll, qh, ql, kh, kl, vh, vl);
    }

    // 3) projections (register GEMM, one 512-thread block per 64-row M-tile)
    if (sepVT) {
        int yMax = QT64 + 2 * KVT64;               // 591
        qkv_proj_kernel<<<yMax, 512, 0, stream>>>(qh, ql, kh, kl, vh, vl, Wh, Wl,
                                                  Qph, Qpl, Kph, Kpl, VTh, VTl, yMax);
    } else {
        int yMax = QT64 + KVT64;                   // 492
        qkv_proj_kernel<<<yMax, 512, 0, stream>>>(qh, ql, kh, kl, vh, vl, Wh, Wl,
                                                  Qph, Qpl, Kph, Kpl, VTh, VTl, yMax);
        v_proj_kernel<<<KVT64, 512, 0, stream>>>(vh, vl, Wh + 2 * WELEM, Wl + 2 * WELEM,
                                                 VTh, VTl);
    }

    // 4) MFMA attention v4 -> oh/ol
    {
        dim3 ga((TQ + 63) / 64, NH, B_SZ);
        attn_mfma4<<<ga, 256, 0, stream>>>(Qph, Qpl, Kph, Kpl, VTh, VTl, oh, ol);
    }

    // 5) output projection + bias -> f32 out
    {
        out_proj_kernel<<<QT64, 512, 0, stream>>>(oh, ol, Wh + 3 * WELEM, Wl + 3 * WELEM,
                                                  b_proj, out);
    }
}

// Round 7
// 271.645 us; speedup vs baseline: 1.5106x; 1.5106x over previous
//
#include <hip/hip_runtime.h>
#include <math.h>

#define B_SZ   32
#define C_DIM  384
#define H_IN   28
#define W_IN   28
#define TQ     785   // 1 + 28*28
#define TKV    197   // 1 + 14*14
#define NH     6
#define HD     64
#define SCALE_F 0.05103103630798287f       // 384^-0.5
#define SCALE_L2E (0.05103103630798287f * 1.4426950408889634f)  // fold log2(e)
#define BN_EPS_F 1e-5f

#define QROWS    25120        // B_SZ*TQ
#define KVROWS   6304         // B_SZ*TKV
#define QROWS_P  25344        // 99*256 (pad to BM=256)
#define KVROWS_P 6528         // 26*256 > 25*256=6400; keep 6528 padding
#define WELEM    147456       // 384*384
#define VT_LD    208          // V^T key stride (16B-aligned rows, >= 197)

#define QT256    99           // 256-row M-tiles for Q rows
#define KVT256   25           // 256-row M-tiles for K/V rows (25*256=6400>=6304)

typedef _Float16 f16;
typedef f16  f16x8 __attribute__((ext_vector_type(8)));
typedef f16  f16x4 __attribute__((ext_vector_type(4)));
typedef float f32x4 __attribute__((ext_vector_type(4)));

__device__ __forceinline__ void split16(float v, f16& h, f16& l) {
    h = (f16)v;
    l = (f16)(v - (float)h);
}

// async global->LDS DMA, 16 B per lane. HW writes at wave-uniform base +
// lane*16 -- every call site computes LDS offset == uniform + lane*16 B.
__device__ __forceinline__ void cp16(void* lds, const void* g) {
    __builtin_amdgcn_global_load_lds(
        (const __attribute__((address_space(1))) unsigned int*)g,
        (__attribute__((address_space(3))) unsigned int*)lds, 16, 0, 0);
}

// XCD-sibling swizzle: 24-block groups; the 3 n0-siblings of one y-tile sit at
// ids {g*24+xcd, +8, +16} -> same XCD under round-robin id%8 placement, so the
// shared A-panel is L2-local. Returns false for pad blocks.
__device__ __forceinline__ bool swz(int id, int yMax, int& y, int& n0) {
    int g = id / 24, w = id - g * 24;
    y = g * 8 + (w & 7);
    n0 = (w >> 3) * 128;
    return y < yMax;
}

// ---------------- prep: weight decompose (+scale fold into w_q) + conv/BN fold --
__global__ __launch_bounds__(256) void prep_kernel(
    const float* __restrict__ wq, const float* __restrict__ wk,
    const float* __restrict__ wv, const float* __restrict__ wp,
    const float* __restrict__ conv_w,
    const float* __restrict__ gamma, const float* __restrict__ beta,
    const float* __restrict__ mean, const float* __restrict__ var,
    f16* __restrict__ Wh, f16* __restrict__ Wl,
    float* __restrict__ wAll)
{
    int idx = blockIdx.x * 256 + threadIdx.x;
    if (idx < 4 * WELEM) {
        int which = idx / WELEM, rem = idx - which * WELEM;
        const float* s = (which == 0) ? wq : (which == 1) ? wk : (which == 2) ? wv : wp;
        float v = s[rem];
        if (which == 0) v *= SCALE_L2E;   // QK^T logits in log2 domain
        f16 h, l;
        split16(v, h, l);
        Wh[idx] = h; Wl[idx] = l;
    } else if (idx < 4 * WELEM + 3 * C_DIM) {
        int k = idx - 4 * WELEM;
        int cv = k / C_DIM, c = k - cv * C_DIM;
        float inv = gamma[k] * rsqrtf(var[k] + BN_EPS_F);
#pragma unroll
        for (int t = 0; t < 9; ++t)
            wAll[cv * 3840 + t * C_DIM + c] = conv_w[(size_t)cv * C_DIM * 9 + c * 9 + t] * inv;
        wAll[cv * 3840 + 9 * C_DIM + c] = beta[k] - mean[k] * inv;
    }
}

// ---------------- fused depthwise conv (Q stride1 + K/V stride2) + cls row -----
__global__ __launch_bounds__(256) void fused_conv_kernel(
    const float* __restrict__ x,
    const float* __restrict__ wAll,
    f16* __restrict__ qh, f16* __restrict__ ql,
    f16* __restrict__ kh, f16* __restrict__ kl,
    f16* __restrict__ vh, f16* __restrict__ vl)
{
    __shared__ float sW[3 * 3840];
    int tid = threadIdx.x;
    int oi = blockIdx.x, b = blockIdx.y;

    if (oi == H_IN) {                 // cls-token path
        if (tid < 96) {
            int c = tid * 4;
            float4 v = *(const float4*)&x[(size_t)b * TQ * C_DIM + c];
            float a[4] = {v.x, v.y, v.z, v.w};
            f16x4 hv, lv;
#pragma unroll
            for (int u = 0; u < 4; ++u) { f16 h, l; split16(a[u], h, l); hv[u] = h; lv[u] = l; }
            size_t oq = (size_t)b * TQ * C_DIM + c;
            size_t okv = (size_t)b * TKV * C_DIM + c;
            *(f16x4*)&qh[oq] = hv;  *(f16x4*)&ql[oq] = lv;
            *(f16x4*)&kh[okv] = hv; *(f16x4*)&kl[okv] = lv;
            *(f16x4*)&vh[okv] = hv; *(f16x4*)&vl[okv] = lv;
        }
        return;
    }

#pragma unroll
    for (int i = 0; i < 12; ++i) {
        int idx = tid + 256 * i;
        if (idx < 2880) cp16(&sW[idx * 4], &wAll[idx * 4]);
    }
    __syncthreads();

    const size_t xb = (size_t)b * TQ * C_DIM + C_DIM;
    bool oi_even = (oi & 1) == 0;

    for (int it = 0; it < 11; ++it) {
        int idx = tid + 256 * it;
        if (idx >= 28 * 96) break;
        int oj = idx / 96, cg = idx - oj * 96;
        int c = cg * 4;

        float4 xv[9];
#pragma unroll
        for (int di = 0; di < 3; ++di) {
            int ii = oi + di - 1;
            bool rok = (ii >= 0) && (ii < H_IN);
#pragma unroll
            for (int dj = 0; dj < 3; ++dj) {
                int jj = oj + dj - 1;
                bool ok = rok && (jj >= 0) && (jj < W_IN);
                xv[di * 3 + dj] = ok ? *(const float4*)&x[xb + ((size_t)ii * W_IN + jj) * C_DIM + c]
                                     : make_float4(0.f, 0.f, 0.f, 0.f);
            }
        }

        {
            float4 acc = *(const float4*)&sW[0 * 3840 + 9 * C_DIM + c];
#pragma unroll
            for (int t = 0; t < 9; ++t) {
                float4 w4 = *(const float4*)&sW[0 * 3840 + t * C_DIM + c];
                acc.x += w4.x * xv[t].x; acc.y += w4.y * xv[t].y;
                acc.z += w4.z * xv[t].z; acc.w += w4.w * xv[t].w;
            }
            f16x4 hv, lv;
            float a[4] = {acc.x, acc.y, acc.z, acc.w};
#pragma unroll
            for (int u = 0; u < 4; ++u) { f16 h, l; split16(a[u], h, l); hv[u] = h; lv[u] = l; }
            size_t off = ((size_t)b * TQ + 1 + oi * W_IN + oj) * C_DIM + c;
            *(f16x4*)&qh[off] = hv;
            *(f16x4*)&ql[off] = lv;
        }

        if (oi_even && ((oj & 1) == 0)) {
            int p = (oi >> 1) * 14 + (oj >> 1);
            size_t off = ((size_t)b * TKV + 1 + p) * C_DIM + c;
#pragma unroll
            for (int cv = 1; cv <= 2; ++cv) {
                float4 acc = *(const float4*)&sW[cv * 3840 + 9 * C_DIM + c];
#pragma unroll
                for (int t = 0; t < 9; ++t) {
                    float4 w4 = *(const float4*)&sW[cv * 3840 + t * C_DIM + c];
                    acc.x += w4.x * xv[t].x; acc.y += w4.y * xv[t].y;
                    acc.z += w4.z * xv[t].z; acc.w += w4.w * xv[t].w;
                }
                f16x4 hv, lv;
                float a[4] = {acc.x, acc.y, acc.z, acc.w};
#pragma unroll
                for (int u = 0; u < 4; ++u) { f16 h, l; split16(a[u], h, l); hv[u] = h; lv[u] = l; }
                if (cv == 1) { *(f16x4*)&kh[off] = hv; *(f16x4*)&kl[off] = lv; }
                else         { *(f16x4*)&vh[off] = hv; *(f16x4*)&vl[off] = lv; }
            }
        }
    }
}

// ---------------- split-f16 MFMA GEMM body (R1 config: best measured 72.7us) --
// 256x128 tile, BK=32, 512 threads (8 waves, per-wave 64x64), triple-buffered
// LDS (144 KB), depth-2 counted-vmcnt prefetch, T2 chunk swizzle (source
// pre-swizzle, linear DMA dest), setprio. Mode 2 now writes SINGLE f16 V^T
// (h only): V/P/O path needs only 2^-12 relative accuracy.
__device__ __forceinline__ void gemm_body(
    const f16* __restrict__ Ah, const f16* __restrict__ Al,
    const f16* __restrict__ Wh, const f16* __restrict__ Wl,
    const float* __restrict__ bias,
    float* __restrict__ Cf, f16* __restrict__ Coh, f16* __restrict__ Col,
    int M, int mode, int m0, int n0)
{
    __shared__ f16 lds[3 * 24576];    // 147456 B -> 1 block/CU (8 waves)

    const int t = threadIdx.x;
    const int wv = t >> 6, lane = t & 63;
    const int wr = (wv >> 1) * 64;    // wave M offset (4 positions)
    const int wc = (wv & 1) * 64;     // wave N offset (2 positions)
    const int lrow = lane & 15, quad = lane >> 4;
    const int qsw = quad ^ ((lrow >> 1) & 3);   // T2 read-side chunk swizzle

    const int sr = t >> 2;
    const int g  = (t & 3) ^ ((t >> 3) & 3);

    const f16* gA0h = Ah + (size_t)(m0 + sr) * 384 + g * 8;
    const f16* gA1h = gA0h + 128 * 384;
    const f16* gA0l = Al + (size_t)(m0 + sr) * 384 + g * 8;
    const f16* gA1l = gA0l + 128 * 384;
    const f16* gBh  = Wh + (size_t)(n0 + sr) * 384 + g * 8;
    const f16* gBl  = Wl + (size_t)(n0 + sr) * 384 + g * 8;

#define STAGE(buf, kk) do {                                   \
        f16* d = lds + (buf) * 24576 + t * 8;                 \
        const int ko = (kk) * 32;                             \
        cp16(d,         gA0h + ko);                           \
        cp16(d + 4096,  gA1h + ko);                           \
        cp16(d + 8192,  gA0l + ko);                           \
        cp16(d + 12288, gA1l + ko);                           \
        cp16(d + 16384, gBh + ko);                            \
        cp16(d + 20480, gBl + ko);                            \
    } while (0)

    f32x4 acc[4][4];
#pragma unroll
    for (int i = 0; i < 4; ++i)
#pragma unroll
        for (int j = 0; j < 4; ++j)
            acc[i][j] = (f32x4){0.f, 0.f, 0.f, 0.f};

    // prologue: two K-steps in flight
    STAGE(0, 0);
    STAGE(1, 1);

#pragma unroll
    for (int kk = 0; kk < 12; ++kk) {
        if (kk == 11) asm volatile("s_waitcnt vmcnt(0)" ::: "memory");
        else          asm volatile("s_waitcnt vmcnt(6)" ::: "memory");
        __builtin_amdgcn_s_barrier();
        __builtin_amdgcn_sched_barrier(0);

        if (kk < 10) {
            STAGE((kk + 2) % 3, kk + 2);
            __builtin_amdgcn_sched_barrier(0);
        }

        const f16* bp = lds + (kk % 3) * 24576;
        f16x8 ah[4], al[4], bh[4], bl[4];
#pragma unroll
        for (int i = 0; i < 4; ++i) {
            int ro = (wr + i * 16 + lrow) * 32 + qsw * 8;
            ah[i] = *(const f16x8*)&bp[ro];
            al[i] = *(const f16x8*)&bp[8192 + ro];
        }
#pragma unroll
        for (int j = 0; j < 4; ++j) {
            int ro = (wc + j * 16 + lrow) * 32 + qsw * 8;
            bh[j] = *(const f16x8*)&bp[16384 + ro];
            bl[j] = *(const f16x8*)&bp[20480 + ro];
        }
        asm volatile("s_waitcnt lgkmcnt(0)" ::: "memory");
        __builtin_amdgcn_sched_barrier(0);     // rule #18: pin MFMAs below wait

        __builtin_amdgcn_s_setprio(1);
#pragma unroll
        for (int i = 0; i < 4; ++i)
#pragma unroll
            for (int j = 0; j < 4; ++j) {
                acc[i][j] = __builtin_amdgcn_mfma_f32_16x16x32_f16(ah[i], bh[j], acc[i][j], 0, 0, 0);
                acc[i][j] = __builtin_amdgcn_mfma_f32_16x16x32_f16(ah[i], bl[j], acc[i][j], 0, 0, 0);
                acc[i][j] = __builtin_amdgcn_mfma_f32_16x16x32_f16(al[i], bh[j], acc[i][j], 0, 0, 0);
            }
        __builtin_amdgcn_s_setprio(0);
    }
#undef STAGE

    // epilogue: C/D layout col=lane&15, row=quad*4+reg
#pragma unroll
    for (int i = 0; i < 4; ++i) {
        int grow0 = m0 + wr + i * 16 + quad * 4;
#pragma unroll
        for (int j = 0; j < 4; ++j) {
            int gcol = n0 + wc + j * 16 + lrow;
            float bb = (bias && mode == 0) ? bias[gcol] : 0.f;
#pragma unroll
            for (int r = 0; r < 4; ++r) {
                int grow = grow0 + r;
                if (grow >= M) continue;
                float v = acc[i][j][r] + bb;
                if (mode == 0) {
                    Cf[(size_t)grow * 384 + gcol] = v;
                } else if (mode == 1) {
                    f16 h, l;
                    split16(v, h, l);
                    Coh[(size_t)grow * 384 + gcol] = h;
                    Col[(size_t)grow * 384 + gcol] = l;
                } else {
                    int bb2 = grow / TKV;
                    int key = grow - bb2 * TKV;
                    size_t off = (size_t)bb2 * 384 * VT_LD + (size_t)gcol * VT_LD + key;
                    Coh[off] = (f16)v;           // single-f16 V^T
                }
            }
        }
    }
}

// ---------------- A-single 2-MFMA GEMM body (out_proj: A = f16-quantized O) ----
// A is already single f16, so ah*(bh+bl) is exact w.r.t. stored A. Triple-buffer,
// counted vmcnt(4) (4 cp16/thread/step). LDS 96 KB. Mode-0 epilogue only.
__device__ __forceinline__ void gemm_body_s(
    const f16* __restrict__ Ah,
    const f16* __restrict__ Wh, const f16* __restrict__ Wl,
    const float* __restrict__ bias, float* __restrict__ Cf,
    int M, int m0, int n0)
{
    __shared__ f16 lds[3 * 16384];    // 96 KB

    const int t = threadIdx.x;
    const int wv = t >> 6, lane = t & 63;
    const int wr = (wv >> 1) * 64;
    const int wc = (wv & 1) * 64;
    const int lrow = lane & 15, quad = lane >> 4;
    const int qsw = quad ^ ((lrow >> 1) & 3);

    const int sr = t >> 2;
    const int g  = (t & 3) ^ ((t >> 3) & 3);

    const f16* gA0 = Ah + (size_t)(m0 + sr) * 384 + g * 8;
    const f16* gA1 = gA0 + 128 * 384;
    const f16* gBh = Wh + (size_t)(n0 + sr) * 384 + g * 8;
    const f16* gBl = Wl + (size_t)(n0 + sr) * 384 + g * 8;

#define STAGE_S(buf, kk) do {                                 \
        f16* d = lds + (buf) * 16384 + t * 8;                 \
        const int ko = (kk) * 32;                             \
        cp16(d,         gA0 + ko);                            \
        cp16(d + 4096,  gA1 + ko);                            \
        cp16(d + 8192,  gBh + ko);                            \
        cp16(d + 12288, gBl + ko);                            \
    } while (0)

    f32x4 acc[4][4];
#pragma unroll
    for (int i = 0; i < 4; ++i)
#pragma unroll
        for (int j = 0; j < 4; ++j)
            acc[i][j] = (f32x4){0.f, 0.f, 0.f, 0.f};

    STAGE_S(0, 0);
    STAGE_S(1, 1);

#pragma unroll
    for (int kk = 0; kk < 12; ++kk) {
        if (kk == 11) asm volatile("s_waitcnt vmcnt(0)" ::: "memory");
        else          asm volatile("s_waitcnt vmcnt(4)" ::: "memory");
        __builtin_amdgcn_s_barrier();
        __builtin_amdgcn_sched_barrier(0);

        if (kk < 10) {
            STAGE_S((kk + 2) % 3, kk + 2);
            __builtin_amdgcn_sched_barrier(0);
        }

        const f16* bp = lds + (kk % 3) * 16384;
        f16x8 ah[4], bh[4], bl[4];
#pragma unroll
        for (int i = 0; i < 4; ++i) {
            int ro = (wr + i * 16 + lrow) * 32 + qsw * 8;
            ah[i] = *(const f16x8*)&bp[ro];
        }
#pragma unroll
        for (int j = 0; j < 4; ++j) {
            int ro = (wc + j * 16 + lrow) * 32 + qsw * 8;
            bh[j] = *(const f16x8*)&bp[8192 + ro];
            bl[j] = *(const f16x8*)&bp[12288 + ro];
        }
        asm volatile("s_waitcnt lgkmcnt(0)" ::: "memory");
        __builtin_amdgcn_sched_barrier(0);

        __builtin_amdgcn_s_setprio(1);
#pragma unroll
        for (int i = 0; i < 4; ++i)
#pragma unroll
            for (int j = 0; j < 4; ++j) {
                acc[i][j] = __builtin_amdgcn_mfma_f32_16x16x32_f16(ah[i], bh[j], acc[i][j], 0, 0, 0);
                acc[i][j] = __builtin_amdgcn_mfma_f32_16x16x32_f16(ah[i], bl[j], acc[i][j], 0, 0, 0);
            }
        __builtin_amdgcn_s_setprio(0);
    }
#undef STAGE_S

#pragma unroll
    for (int i = 0; i < 4; ++i) {
        int grow0 = m0 + wr + i * 16 + quad * 4;
#pragma unroll
        for (int j = 0; j < 4; ++j) {
            int gcol = n0 + wc + j * 16 + lrow;
            float bb = bias[gcol];
#pragma unroll
            for (int r = 0; r < 4; ++r) {
                int grow = grow0 + r;
                if (grow >= M) continue;
                Cf[(size_t)grow * 384 + gcol] = acc[i][j][r] + bb;
            }
        }
    }
}

// Q/K/V projections, swizzled 1-D grid. y in [0,99) Q, [99,124) K, [124,149) V.
__global__ __launch_bounds__(512, 2) void qkv_proj_kernel(
    const f16* __restrict__ qh, const f16* __restrict__ ql,
    const f16* __restrict__ kh, const f16* __restrict__ kl,
    const f16* __restrict__ vh, const f16* __restrict__ vl,
    const f16* __restrict__ Wh, const f16* __restrict__ Wl,
    f16* __restrict__ Qph, f16* __restrict__ Qpl,
    f16* __restrict__ Kph, f16* __restrict__ Kpl,
    f16* __restrict__ VTh,
    int yMax)
{
    int y, n0;
    if (!swz(blockIdx.x, yMax, y, n0)) return;
    if (y < QT256)
        gemm_body(qh, ql, Wh, Wl, nullptr, nullptr, Qph, Qpl, QROWS, 1, y * 256, n0);
    else if (y < QT256 + KVT256)
        gemm_body(kh, kl, Wh + WELEM, Wl + WELEM, nullptr, nullptr, Kph, Kpl,
                  KVROWS, 1, (y - QT256) * 256, n0);
    else
        gemm_body(vh, vl, Wh + 2 * WELEM, Wl + 2 * WELEM, nullptr, nullptr, VTh, nullptr,
                  KVROWS, 2, (y - QT256 - KVT256) * 256, n0);
}

// fallback V projection (aliased-VT workspace layout), swizzled
__global__ __launch_bounds__(512, 2) void v_proj_kernel(
    const f16* __restrict__ vh, const f16* __restrict__ vl,
    const f16* __restrict__ Wh, const f16* __restrict__ Wl,
    f16* __restrict__ VTh)
{
    int y, n0;
    if (!swz(blockIdx.x, KVT256, y, n0)) return;
    gemm_body(vh, vl, Wh, Wl, nullptr, nullptr, VTh, nullptr, KVROWS, 2, y * 256, n0);
}

__global__ __launch_bounds__(512, 2) void out_proj_kernel(
    const f16* __restrict__ Ah,
    const f16* __restrict__ Wh, const f16* __restrict__ Wl,
    const float* __restrict__ bias, float* __restrict__ Cf)
{
    int y, n0;
    if (!swz(blockIdx.x, QT256, y, n0)) return;
    gemm_body_s(Ah, Wh, Wl, bias, Cf, QROWS, y * 256, n0);
}

// ---------------- MFMA attention v6: v4 QK phase + single-f16 P/V/O PV phase ---
// QK^T: Q,K h+l (logit precision), verbatim v4. PV: V^T single f16 staged into
// sKh/sKl as a TRUE double buffer (tile vt+2 issued right after the sync that
// frees its buffer -> every VT DMA hides under a PV compute phase or softmax),
// P single f16 (1 MFMA per (ks,j), was 3), O written single f16.
__global__ __launch_bounds__(256) void attn_mfma6(
    const f16* __restrict__ Qh, const f16* __restrict__ Ql,
    const f16* __restrict__ Kh, const f16* __restrict__ Kl,
    const f16* __restrict__ VTh,
    f16* __restrict__ Oh)
{
    __shared__ f16 sQh[2][64][32];
    __shared__ f16 sQl[2][64][32];
    __shared__ f16 sKh[2][64][32];   // QK: Kh; PV: VT buffer (even vt)
    __shared__ f16 sKl[2][64][32];   // QK: Kl; PV: VT buffer (odd vt)
    __shared__ float sPs[64][68];

    int t = threadIdx.x;
    int wv = t >> 6, lane = t & 63;
    int c = lane & 15, quad = lane >> 4;
    int wq0 = wv * 16;
    int h = blockIdx.y, b = blockIdx.z;
    int q0 = blockIdx.x * 64;

    const size_t qbase  = (size_t)b * TQ * C_DIM + h * HD;
    const size_t kbase  = (size_t)b * TKV * C_DIM + h * HD;
    const size_t vtbase = (size_t)b * 384 * VT_LD + (size_t)h * HD * VT_LD;

#pragma unroll
    for (int i = 0; i < 2; ++i) {
        int idx = t + 256 * i;
        int ks = idx >> 8, row = (idx >> 2) & 63, sg = (idx & 3) * 8;
        cp16(&sQh[ks][row][sg], &Qh[qbase + (size_t)(q0 + row) * C_DIM + ks * 32 + sg]);
        cp16(&sQl[ks][row][sg], &Ql[qbase + (size_t)(q0 + row) * C_DIM + ks * 32 + sg]);
    }

    f32x4 s[4][4];
#pragma unroll
    for (int kt = 0; kt < 4; ++kt)
#pragma unroll
        for (int j = 0; j < 4; ++j)
            s[kt][j] = (f32x4){0.f, 0.f, 0.f, 0.f};

#pragma unroll
    for (int kt = 0; kt < 4; ++kt) {
        if (kt) __syncthreads();
#pragma unroll
        for (int i = 0; i < 2; ++i) {
            int idx = t + 256 * i;
            int ks = idx >> 8, row = (idx >> 2) & 63, sg = (idx & 3) * 8;
            cp16(&sKh[ks][row][sg], &Kh[kbase + (size_t)(kt * 64 + row) * C_DIM + ks * 32 + sg]);
            cp16(&sKl[ks][row][sg], &Kl[kbase + (size_t)(kt * 64 + row) * C_DIM + ks * 32 + sg]);
        }
        __syncthreads();

#pragma unroll
        for (int ks = 0; ks < 2; ++ks) {
            f16x8 qh8 = *(const f16x8*)&sQh[ks][wq0 + c][quad * 8];
            f16x8 ql8 = *(const f16x8*)&sQl[ks][wq0 + c][quad * 8];
#pragma unroll
            for (int j = 0; j < 4; ++j) {
                f16x8 kh8 = *(const f16x8*)&sKh[ks][j * 16 + c][quad * 8];
                f16x8 kl8 = *(const f16x8*)&sKl[ks][j * 16 + c][quad * 8];
                s[kt][j] = __builtin_amdgcn_mfma_f32_16x16x32_f16(qh8, kh8, s[kt][j], 0, 0, 0);
                s[kt][j] = __builtin_amdgcn_mfma_f32_16x16x32_f16(qh8, kl8, s[kt][j], 0, 0, 0);
                s[kt][j] = __builtin_amdgcn_mfma_f32_16x16x32_f16(ql8, kh8, s[kt][j], 0, 0, 0);
            }
        }
    }

    __syncthreads();                   // all S frag reads done: K panels free

    // VT0 -> sKh, VT1 -> sKl: both DMAs ride under the softmax VALU
#pragma unroll
    for (int i = 0; i < 2; ++i) {
        int idx = t + 256 * i;
        int ks = idx >> 8, row = (idx >> 2) & 63, sg = (idx & 3) * 8;
        cp16(&sKh[ks][row][sg], &VTh[vtbase + (size_t)row * VT_LD + ks * 32 + sg]);
        cp16(&sKl[ks][row][sg], &VTh[vtbase + (size_t)row * VT_LD + 64 + ks * 32 + sg]);
    }

#pragma unroll
    for (int r = 0; r < 4; ++r) {
        s[3][0][r] = (c < 5) ? s[3][0][r] : -1e30f;
        s[3][1][r] = -1e30f;
        s[3][2][r] = -1e30f;
        s[3][3][r] = -1e30f;
    }

    float inv_r[4];
#pragma unroll
    for (int r = 0; r < 4; ++r) {
        float mx = -1e30f;
#pragma unroll
        for (int kt = 0; kt < 4; ++kt)
#pragma unroll
            for (int j = 0; j < 4; ++j)
                mx = fmaxf(mx, s[kt][j][r]);
        mx = fmaxf(mx, __shfl_xor(mx, 1));
        mx = fmaxf(mx, __shfl_xor(mx, 2));
        mx = fmaxf(mx, __shfl_xor(mx, 4));
        mx = fmaxf(mx, __shfl_xor(mx, 8));
        float sum = 0.f;
#pragma unroll
        for (int kt = 0; kt < 4; ++kt)
#pragma unroll
            for (int j = 0; j < 4; ++j) {
                float pv = exp2f(s[kt][j][r] - mx);
                s[kt][j][r] = pv;
                sum += pv;
            }
        sum += __shfl_xor(sum, 1);
        sum += __shfl_xor(sum, 2);
        sum += __shfl_xor(sum, 4);
        sum += __shfl_xor(sum, 8);
        inv_r[r] = 1.f / sum;
    }

    f32x4 o[4];
#pragma unroll
    for (int j = 0; j < 4; ++j) o[j] = (f32x4){0.f, 0.f, 0.f, 0.f};

#define SPS_WRITE(VT) do {                                           \
        _Pragma("unroll") for (int r = 0; r < 4; ++r)                \
            _Pragma("unroll") for (int j = 0; j < 4; ++j)            \
                sPs[wq0 + quad * 4 + r][j * 16 + c] = s[VT][j][r];   \
    } while (0)

#define VT_ISSUE2(DST, VT) do {                                                \
        _Pragma("unroll") for (int i = 0; i < 2; ++i) {                        \
            int idx = t + 256 * i;                                             \
            int ks = idx >> 8, row = (idx >> 2) & 63, sg = (idx & 3) * 8;      \
            cp16(&DST[ks][row][sg],                                            \
                 &VTh[vtbase + (size_t)row * VT_LD + (VT) * 64 + ks * 32 + sg]); \
        } } while (0)

#define PV_TILE_S(BUF) do {                                                    \
        _Pragma("unroll") for (int ks = 0; ks < 2; ++ks) {                     \
            float4 p0 = *(const float4*)&sPs[wq0 + c][ks * 32 + quad * 8];     \
            float4 p1 = *(const float4*)&sPs[wq0 + c][ks * 32 + quad * 8 + 4]; \
            float pf[8] = {p0.x, p0.y, p0.z, p0.w, p1.x, p1.y, p1.z, p1.w};    \
            f16x8 p8;                                                          \
            _Pragma("unroll") for (int ii = 0; ii < 8; ++ii) p8[ii] = (f16)pf[ii]; \
            _Pragma("unroll") for (int j = 0; j < 4; ++j) {                    \
                f16x8 vv8 = *(const f16x8*)&BUF[ks][j * 16 + c][quad * 8];     \
                o[j] = __builtin_amdgcn_mfma_f32_16x16x32_f16(p8, vv8, o[j], 0, 0, 0); \
            } } } while (0)

    __syncthreads();                   // VT0+VT1 complete (softmax covered them)
    SPS_WRITE(0);
    PV_TILE_S(sKh);
    __syncthreads();                   // sKh reads done
    VT_ISSUE2(sKh, 2);                 // VT2 DMA rides under PV(1)
    SPS_WRITE(1);
    PV_TILE_S(sKl);
    __syncthreads();                   // drains VT2; sKl reads done
    VT_ISSUE2(sKl, 3);                 // VT3 DMA rides under PV(2)
    SPS_WRITE(2);
    PV_TILE_S(sKh);
    __syncthreads();                   // drains VT3
    SPS_WRITE(3);
    PV_TILE_S(sKl);

#pragma unroll
    for (int r = 0; r < 4; ++r) {
        int gq = q0 + wq0 + quad * 4 + r;
        if (gq >= TQ) continue;
        float inv = inv_r[r];
#pragma unroll
        for (int j = 0; j < 4; ++j) {
            size_t off = (size_t)(b * TQ + gq) * C_DIM + h * HD + j * 16 + c;
            Oh[off] = (f16)(o[j][r] * inv);    // single-f16 O
        }
    }
#undef SPS_WRITE
#undef VT_ISSUE2
#undef PV_TILE_S
}

extern "C" void kernel_launch(void* const* d_in, const int* in_sizes, int n_in,
                              void* d_out, int out_size, void* d_ws, size_t ws_size,
                              hipStream_t stream) {
    const float* x       = (const float*)d_in[0];
    const float* conv_w  = (const float*)d_in[1];
    const float* bn_g    = (const float*)d_in[2];
    const float* bn_b    = (const float*)d_in[3];
    const float* bn_m    = (const float*)d_in[4];
    const float* bn_v    = (const float*)d_in[5];
    const float* w_q     = (const float*)d_in[6];
    const float* w_k     = (const float*)d_in[7];
    const float* w_v     = (const float*)d_in[8];
    const float* w_proj  = (const float*)d_in[9];
    const float* b_proj  = (const float*)d_in[10];
    float* out = (float*)d_out;

    const size_t QSZ   = (size_t)QROWS_P * 384 * sizeof(f16);
    const size_t KVSZ  = (size_t)KVROWS_P * 384 * sizeof(f16);
    const size_t WSZ   = 4 * (size_t)WELEM * sizeof(f16);
    const size_t VTSZ  = (size_t)B_SZ * 384 * VT_LD * sizeof(f16);   // single f16 now
    const size_t WALLS = 3 * 3840 * sizeof(float);

    char* p = (char*)d_ws;
    f16* qh  = (f16*)p; p += QSZ;
    f16* ql  = (f16*)p; p += QSZ;
    f16* vh  = (f16*)p; p += KVSZ;
    f16* vl  = (f16*)p; p += KVSZ;
    f16* kh  = (f16*)p; p += KVSZ;
    f16* kl  = (f16*)p; p += KVSZ;
    f16* Wh  = (f16*)p; p += WSZ;
    f16* Wl  = (f16*)p; p += WSZ;
    f16* Qph = (f16*)p; p += QSZ;
    f16* Qpl = (f16*)p; p += QSZ;
    f16* Kph = (f16*)p; p += KVSZ;
    f16* Kpl = (f16*)p; p += KVSZ;
    float* wAll = (float*)p; p += WALLS;

    size_t used = (size_t)(p - (char*)d_ws);
    bool sepVT = (ws_size >= used + VTSZ);
    f16* VTh = sepVT ? (f16*)p : kh;   // fallback: kh(+kl) region dead post-qkv
    f16* oh = qh;                      // O aliases qh (read complete after attn input stage)

    // 1) prep
    {
        int total = 4 * WELEM + 3 * C_DIM;
        prep_kernel<<<(total + 255) / 256, 256, 0, stream>>>(
            w_q, w_k, w_v, w_proj, conv_w, bn_g, bn_b, bn_m, bn_v, Wh, Wl, wAll);
    }

    // 2) fused conv (Q + K + V + cls)
    {
        dim3 gc(H_IN + 1, B_SZ);
        fused_conv_kernel<<<gc, 256, 0, stream>>>(x, wAll, qh, ql, kh, kl, vh, vl);
    }

    // 3) projections (swizzled 1-D grids; blocks = ceil(yMax/8)*24)
    if (sepVT) {
        int yMax = QT256 + 2 * KVT256;             // 149
        int nb = ((yMax + 7) / 8) * 24;            // 456
        qkv_proj_kernel<<<nb, 512, 0, stream>>>(qh, ql, kh, kl, vh, vl, Wh, Wl,
                                                Qph, Qpl, Kph, Kpl, VTh, yMax);
    } else {
        int yMax = QT256 + KVT256;                 // 124
        int nb = ((yMax + 7) / 8) * 24;            // 384
        qkv_proj_kernel<<<nb, 512, 0, stream>>>(qh, ql, kh, kl, vh, vl, Wh, Wl,
                                                Qph, Qpl, Kph, Kpl, VTh, yMax);
        int nbv = ((KVT256 + 7) / 8) * 24;         // 96
        v_proj_kernel<<<nbv, 512, 0, stream>>>(vh, vl, Wh + 2 * WELEM, Wl + 2 * WELEM,
                                               VTh);
    }

    // 4) MFMA attention v6 -> oh (single f16)
    {
        dim3 ga((TQ + 63) / 64, NH, B_SZ);
        attn_mfma6<<<ga, 256, 0, stream>>>(Qph, Qpl, Kph, Kpl, VTh, oh);
    }

    // 5) output projection + bias -> f32 out (A-single 2-MFMA body)
    {
        int nb = ((QT256 + 7) / 8) * 24;           // 312
        out_proj_kernel<<<nb, 512, 0, stream>>>(oh, Wh + 3 * WELEM, Wl + 3 * WELEM,
                                                b_proj, out);
    }
}

// Round 9
// 243.272 us; speedup vs baseline: 1.6867x; 1.1166x over previous
//
#include <hip/hip_runtime.h>
#include <math.h>

#define B_SZ   32
#define C_DIM  384
#define H_IN   28
#define W_IN   28
#define TQ     785   // 1 + 28*28
#define TKV    197   // 1 + 14*14
#define NH     6
#define HD     64
#define SCALE_F 0.05103103630798287f       // 384^-0.5
#define SCALE_L2E (0.05103103630798287f * 1.4426950408889634f)  // fold log2(e)
#define BN_EPS_F 1e-5f

#define QROWS    25120        // B_SZ*TQ
#define KVROWS   6304         // B_SZ*TKV
#define QROWS_P  25344        // 99*256 (pad to BM=256)
#define KVROWS_P 6528
#define WELEM    147456       // 384*384
#define VT_LD    208          // V^T key stride (16B-aligned rows, >= 197)

#define QT256    99           // 256-row M-tiles for Q rows
#define KVT256   25           // 256-row M-tiles for K/V rows

typedef _Float16 f16;
typedef f16  f16x8 __attribute__((ext_vector_type(8)));
typedef f16  f16x4 __attribute__((ext_vector_type(4)));
typedef float f32x4 __attribute__((ext_vector_type(4)));

__device__ __forceinline__ void split16(float v, f16& h, f16& l) {
    h = (f16)v;
    l = (f16)(v - (float)h);
}

// async global->LDS DMA, 16 B per lane. HW writes at wave-uniform base +
// lane*16 -- every call site computes LDS offset == uniform + lane*16 B.
__device__ __forceinline__ void cp16(void* lds, const void* g) {
    __builtin_amdgcn_global_load_lds(
        (const __attribute__((address_space(1))) unsigned int*)g,
        (__attribute__((address_space(3))) unsigned int*)lds, 16, 0, 0);
}

// XCD-sibling swizzle: 24-block groups; the 3 n0-siblings of one y-tile sit at
// ids {g*24+xcd, +8, +16} -> same XCD under round-robin id%8 placement.
__device__ __forceinline__ bool swz(int id, int yMax, int& y, int& n0) {
    int g = id / 24, w = id - g * 24;
    y = g * 8 + (w & 7);
    n0 = (w >> 3) * 128;
    return y < yMax;
}

// ---------------- prep: weight decompose (+scale fold into w_q) + conv/BN fold --
__global__ __launch_bounds__(256) void prep_kernel(
    const float* __restrict__ wq, const float* __restrict__ wk,
    const float* __restrict__ wv, const float* __restrict__ wp,
    const float* __restrict__ conv_w,
    const float* __restrict__ gamma, const float* __restrict__ beta,
    const float* __restrict__ mean, const float* __restrict__ var,
    f16* __restrict__ Wh, f16* __restrict__ Wl,
    float* __restrict__ wAll)
{
    int idx = blockIdx.x * 256 + threadIdx.x;
    if (idx < 4 * WELEM) {
        int which = idx / WELEM, rem = idx - which * WELEM;
        const float* s = (which == 0) ? wq : (which == 1) ? wk : (which == 2) ? wv : wp;
        float v = s[rem];
        if (which == 0) v *= SCALE_L2E;   // QK^T logits in log2 domain
        f16 h, l;
        split16(v, h, l);
        Wh[idx] = h; Wl[idx] = l;
    } else if (idx < 4 * WELEM + 3 * C_DIM) {
        int k = idx - 4 * WELEM;
        int cv = k / C_DIM, c = k - cv * C_DIM;
        float inv = gamma[k] * rsqrtf(var[k] + BN_EPS_F);
#pragma unroll
        for (int t = 0; t < 9; ++t)
            wAll[cv * 3840 + t * C_DIM + c] = conv_w[(size_t)cv * C_DIM * 9 + c * 9 + t] * inv;
        wAll[cv * 3840 + 9 * C_DIM + c] = beta[k] - mean[k] * inv;
    }
}

// ---------------- fused depthwise conv, SINGLE-f16 outputs ---------------------
__global__ __launch_bounds__(256) void fused_conv_kernel(
    const float* __restrict__ x,
    const float* __restrict__ wAll,
    f16* __restrict__ q, f16* __restrict__ k, f16* __restrict__ v)
{
    __shared__ float sW[3 * 3840];
    int tid = threadIdx.x;
    int oi = blockIdx.x, b = blockIdx.y;

    if (oi == H_IN) {                 // cls-token path
        if (tid < 96) {
            int c = tid * 4;
            float4 vv = *(const float4*)&x[(size_t)b * TQ * C_DIM + c];
            float a[4] = {vv.x, vv.y, vv.z, vv.w};
            f16x4 hv;
#pragma unroll
            for (int u = 0; u < 4; ++u) hv[u] = (f16)a[u];
            size_t oq = (size_t)b * TQ * C_DIM + c;
            size_t okv = (size_t)b * TKV * C_DIM + c;
            *(f16x4*)&q[oq] = hv;
            *(f16x4*)&k[okv] = hv;
            *(f16x4*)&v[okv] = hv;
        }
        return;
    }

#pragma unroll
    for (int i = 0; i < 12; ++i) {
        int idx = tid + 256 * i;
        if (idx < 2880) cp16(&sW[idx * 4], &wAll[idx * 4]);
    }
    __syncthreads();

    const size_t xb = (size_t)b * TQ * C_DIM + C_DIM;
    bool oi_even = (oi & 1) == 0;

    for (int it = 0; it < 11; ++it) {
        int idx = tid + 256 * it;
        if (idx >= 28 * 96) break;
        int oj = idx / 96, cg = idx - oj * 96;
        int c = cg * 4;

        float4 xv[9];
#pragma unroll
        for (int di = 0; di < 3; ++di) {
            int ii = oi + di - 1;
            bool rok = (ii >= 0) && (ii < H_IN);
#pragma unroll
            for (int dj = 0; dj < 3; ++dj) {
                int jj = oj + dj - 1;
                bool ok = rok && (jj >= 0) && (jj < W_IN);
                xv[di * 3 + dj] = ok ? *(const float4*)&x[xb + ((size_t)ii * W_IN + jj) * C_DIM + c]
                                     : make_float4(0.f, 0.f, 0.f, 0.f);
            }
        }

        {
            float4 acc = *(const float4*)&sW[0 * 3840 + 9 * C_DIM + c];
#pragma unroll
            for (int t = 0; t < 9; ++t) {
                float4 w4 = *(const float4*)&sW[0 * 3840 + t * C_DIM + c];
                acc.x += w4.x * xv[t].x; acc.y += w4.y * xv[t].y;
                acc.z += w4.z * xv[t].z; acc.w += w4.w * xv[t].w;
            }
            f16x4 hv;
            hv[0] = (f16)acc.x; hv[1] = (f16)acc.y; hv[2] = (f16)acc.z; hv[3] = (f16)acc.w;
            size_t off = ((size_t)b * TQ + 1 + oi * W_IN + oj) * C_DIM + c;
            *(f16x4*)&q[off] = hv;
        }

        if (oi_even && ((oj & 1) == 0)) {
            int p = (oi >> 1) * 14 + (oj >> 1);
            size_t off = ((size_t)b * TKV + 1 + p) * C_DIM + c;
#pragma unroll
            for (int cv = 1; cv <= 2; ++cv) {
                float4 acc = *(const float4*)&sW[cv * 3840 + 9 * C_DIM + c];
#pragma unroll
                for (int t = 0; t < 9; ++t) {
                    float4 w4 = *(const float4*)&sW[cv * 3840 + t * C_DIM + c];
                    acc.x += w4.x * xv[t].x; acc.y += w4.y * xv[t].y;
                    acc.z += w4.z * xv[t].z; acc.w += w4.w * xv[t].w;
                }
                f16x4 hv;
                hv[0] = (f16)acc.x; hv[1] = (f16)acc.y; hv[2] = (f16)acc.z; hv[3] = (f16)acc.w;
                if (cv == 1) *(f16x4*)&k[off] = hv;
                else         *(f16x4*)&v[off] = hv;
            }
        }
    }
}

// ---------------- A-single 2-MFMA GEMM body (all projections) ------------------
// A single f16 (activations), W h+l (L2-resident, byte-free precision):
// out = a*(wh+wl) is exact w.r.t. the stored A. 256x128 tile, BK=32, 512 thr,
// triple-buffered 96 KB LDS, depth-2 counted vmcnt(4), T2 chunk swizzle,
// setprio. Per-buffer (f16 units, 16384): A [0,8192) 256x32, Bh [8192,12288),
// Bl [12288,16384). Modes: 0 = f32+bias, 1 = single-f16 row-major, 2 = VT.
__device__ __forceinline__ void gemm_body_s(
    const f16* __restrict__ Ah,
    const f16* __restrict__ Wh, const f16* __restrict__ Wl,
    const float* __restrict__ bias,
    float* __restrict__ Cf, f16* __restrict__ Co,
    int M, int mode, int m0, int n0)
{
    __shared__ f16 lds[3 * 16384];    // 96 KB

    const int t = threadIdx.x;
    const int wv = t >> 6, lane = t & 63;
    const int wr = (wv >> 1) * 64;
    const int wc = (wv & 1) * 64;
    const int lrow = lane & 15, quad = lane >> 4;
    const int qsw = quad ^ ((lrow >> 1) & 3);   // T2 read-side chunk swizzle

    const int sr = t >> 2;
    const int g  = (t & 3) ^ ((t >> 3) & 3);

    const f16* gA0 = Ah + (size_t)(m0 + sr) * 384 + g * 8;
    const f16* gA1 = gA0 + 128 * 384;
    const f16* gBh = Wh + (size_t)(n0 + sr) * 384 + g * 8;
    const f16* gBl = Wl + (size_t)(n0 + sr) * 384 + g * 8;

#define STAGE_S(buf, kk) do {                                 \
        f16* d = lds + (buf) * 16384 + t * 8;                 \
        const int ko = (kk) * 32;                             \
        cp16(d,         gA0 + ko);                            \
        cp16(d + 4096,  gA1 + ko);                            \
        cp16(d + 8192,  gBh + ko);                            \
        cp16(d + 12288, gBl + ko);                            \
    } while (0)

    f32x4 acc[4][4];
#pragma unroll
    for (int i = 0; i < 4; ++i)
#pragma unroll
        for (int j = 0; j < 4; ++j)
            acc[i][j] = (f32x4){0.f, 0.f, 0.f, 0.f};

    STAGE_S(0, 0);
    STAGE_S(1, 1);

#pragma unroll
    for (int kk = 0; kk < 12; ++kk) {
        if (kk == 11) asm volatile("s_waitcnt vmcnt(0)" ::: "memory");
        else          asm volatile("s_waitcnt vmcnt(4)" ::: "memory");
        __builtin_amdgcn_s_barrier();
        __builtin_amdgcn_sched_barrier(0);

        if (kk < 10) {
            STAGE_S((kk + 2) % 3, kk + 2);
            __builtin_amdgcn_sched_barrier(0);
        }

        const f16* bp = lds + (kk % 3) * 16384;
        f16x8 ah[4], bh[4], bl[4];
#pragma unroll
        for (int i = 0; i < 4; ++i) {
            int ro = (wr + i * 16 + lrow) * 32 + qsw * 8;
            ah[i] = *(const f16x8*)&bp[ro];
        }
#pragma unroll
        for (int j = 0; j < 4; ++j) {
            int ro = (wc + j * 16 + lrow) * 32 + qsw * 8;
            bh[j] = *(const f16x8*)&bp[8192 + ro];
            bl[j] = *(const f16x8*)&bp[12288 + ro];
        }
        asm volatile("s_waitcnt lgkmcnt(0)" ::: "memory");
        __builtin_amdgcn_sched_barrier(0);     // rule #18: pin MFMAs below wait

        __builtin_amdgcn_s_setprio(1);
#pragma unroll
        for (int i = 0; i < 4; ++i)
#pragma unroll
            for (int j = 0; j < 4; ++j) {
                acc[i][j] = __builtin_amdgcn_mfma_f32_16x16x32_f16(ah[i], bh[j], acc[i][j], 0, 0, 0);
                acc[i][j] = __builtin_amdgcn_mfma_f32_16x16x32_f16(ah[i], bl[j], acc[i][j], 0, 0, 0);
            }
        __builtin_amdgcn_s_setprio(0);
    }
#undef STAGE_S

    // epilogue: C/D layout col=lane&15, row=quad*4+reg
#pragma unroll
    for (int i = 0; i < 4; ++i) {
        int grow0 = m0 + wr + i * 16 + quad * 4;
#pragma unroll
        for (int j = 0; j < 4; ++j) {
            int gcol = n0 + wc + j * 16 + lrow;
            float bb = (bias && mode == 0) ? bias[gcol] : 0.f;
#pragma unroll
            for (int r = 0; r < 4; ++r) {
                int grow = grow0 + r;
                if (grow >= M) continue;
                float vv = acc[i][j][r] + bb;
                if (mode == 0) {
                    Cf[(size_t)grow * 384 + gcol] = vv;
                } else if (mode == 1) {
                    Co[(size_t)grow * 384 + gcol] = (f16)vv;
                } else {
                    int bb2 = grow / TKV;
                    int key = grow - bb2 * TKV;
                    size_t off = (size_t)bb2 * 384 * VT_LD + (size_t)gcol * VT_LD + key;
                    Co[off] = (f16)vv;
                }
            }
        }
    }
}

// Q/K/V projections, swizzled 1-D grid. y in [0,99) Q, [99,124) K, [124,149) V.
__global__ __launch_bounds__(512, 2) void qkv_proj_kernel(
    const f16* __restrict__ q, const f16* __restrict__ k, const f16* __restrict__ v,
    const f16* __restrict__ Wh, const f16* __restrict__ Wl,
    f16* __restrict__ Qp, f16* __restrict__ Kp, f16* __restrict__ VT,
    int yMax)
{
    int y, n0;
    if (!swz(blockIdx.x, yMax, y, n0)) return;
    if (y < QT256)
        gemm_body_s(q, Wh, Wl, nullptr, nullptr, Qp, QROWS, 1, y * 256, n0);
    else if (y < QT256 + KVT256)
        gemm_body_s(k, Wh + WELEM, Wl + WELEM, nullptr, nullptr, Kp,
                    KVROWS, 1, (y - QT256) * 256, n0);
    else
        gemm_body_s(v, Wh + 2 * WELEM, Wl + 2 * WELEM, nullptr, nullptr, VT,
                    KVROWS, 2, (y - QT256 - KVT256) * 256, n0);
}

// fallback V projection (aliased-VT workspace layout), swizzled
__global__ __launch_bounds__(512, 2) void v_proj_kernel(
    const f16* __restrict__ v,
    const f16* __restrict__ Wh, const f16* __restrict__ Wl,
    f16* __restrict__ VT)
{
    int y, n0;
    if (!swz(blockIdx.x, KVT256, y, n0)) return;
    gemm_body_s(v, Wh, Wl, nullptr, nullptr, VT, KVROWS, 2, y * 256, n0);
}

__global__ __launch_bounds__(512, 2) void out_proj_kernel(
    const f16* __restrict__ Ah,
    const f16* __restrict__ Wh, const f16* __restrict__ Wl,
    const float* __restrict__ bias, float* __restrict__ Cf)
{
    int y, n0;
    if (!swz(blockIdx.x, QT256, y, n0)) return;
    gemm_body_s(Ah, Wh, Wl, bias, Cf, nullptr, QROWS, 0, y * 256, n0);
}

// ---------------- MFMA attention v7: all-single-f16, double-buffered K & VT ----
// Q,K,VT single f16 -> QK = 1 MFMA/fragment (was 3), PV = 1 (R7). K tiles
// double-buffer across sKa/sKb so each K DMA rides under the previous QK
// compute; VT pipeline as R7 v6. LDS 41.4 KB -> 3 blocks/CU.
__global__ __launch_bounds__(256) void attn_mfma7(
    const f16* __restrict__ Qp, const f16* __restrict__ Kp,
    const f16* __restrict__ VT, f16* __restrict__ Oh)
{
    __shared__ f16 sQ[2][64][32];
    __shared__ f16 sKa[2][64][32];
    __shared__ f16 sKb[2][64][32];
    __shared__ float sPs[64][68];

    int t = threadIdx.x;
    int wv = t >> 6, lane = t & 63;
    int c = lane & 15, quad = lane >> 4;
    int wq0 = wv * 16;
    int h = blockIdx.y, b = blockIdx.z;
    int q0 = blockIdx.x * 64;

    const size_t qbase  = (size_t)b * TQ * C_DIM + h * HD;
    const size_t kbase  = (size_t)b * TKV * C_DIM + h * HD;
    const size_t vtbase = (size_t)b * 384 * VT_LD + (size_t)h * HD * VT_LD;

    // tile stage: 8 KB / tile, 2 cp16 per thread
#define STAGE_T(DST, EXPR) do {                                      \
        _Pragma("unroll") for (int i = 0; i < 2; ++i) {              \
            int idx = t + 256 * i;                                   \
            int ks = idx >> 8, row = (idx >> 2) & 63, sg = (idx & 3) * 8; \
            cp16(&DST[ks][row][sg], (EXPR));                         \
        } } while (0)

#define QK(KT, BUF) do {                                             \
        __builtin_amdgcn_s_setprio(1);                               \
        _Pragma("unroll") for (int ks = 0; ks < 2; ++ks) {           \
            _Pragma("unroll") for (int j = 0; j < 4; ++j) {          \
                f16x8 k8 = *(const f16x8*)&BUF[ks][j * 16 + c][quad * 8]; \
                s[KT][j] = __builtin_amdgcn_mfma_f32_16x16x32_f16(q8[ks], k8, s[KT][j], 0, 0, 0); \
            } }                                                      \
        __builtin_amdgcn_s_setprio(0);                               \
    } while (0)

    f32x4 s[4][4];
#pragma unroll
    for (int kt = 0; kt < 4; ++kt)
#pragma unroll
        for (int j = 0; j < 4; ++j)
            s[kt][j] = (f32x4){0.f, 0.f, 0.f, 0.f};

    STAGE_T(sQ,  &Qp[qbase + (size_t)(q0 + row) * C_DIM + ks * 32 + sg]);
    STAGE_T(sKa, &Kp[kbase + (size_t)(0 * 64 + row) * C_DIM + ks * 32 + sg]);
    __syncthreads();                   // Q + K0 ready

    f16x8 q8[2];
#pragma unroll
    for (int ks = 0; ks < 2; ++ks)
        q8[ks] = *(const f16x8*)&sQ[ks][wq0 + c][quad * 8];

    STAGE_T(sKb, &Kp[kbase + (size_t)(1 * 64 + row) * C_DIM + ks * 32 + sg]);
    QK(0, sKa);
    __syncthreads();                   // K1 done; sKa reads done
    STAGE_T(sKa, &Kp[kbase + (size_t)(2 * 64 + row) * C_DIM + ks * 32 + sg]);
    QK(1, sKb);
    __syncthreads();                   // K2 done; sKb reads done
    STAGE_T(sKb, &Kp[kbase + (size_t)(3 * 64 + row) * C_DIM + ks * 32 + sg]);
    QK(2, sKa);
    __syncthreads();                   // K3 done; sKa reads done
    QK(3, sKb);
    __syncthreads();                   // sKb reads done: both buffers free

    // VT0/VT1 DMAs ride under the softmax VALU
    STAGE_T(sKa, &VT[vtbase + (size_t)row * VT_LD + 0 * 64 + ks * 32 + sg]);
    STAGE_T(sKb, &VT[vtbase + (size_t)row * VT_LD + 1 * 64 + ks * 32 + sg]);

#pragma unroll
    for (int r = 0; r < 4; ++r) {
        s[3][0][r] = (c < 5) ? s[3][0][r] : -1e30f;
        s[3][1][r] = -1e30f;
        s[3][2][r] = -1e30f;
        s[3][3][r] = -1e30f;
    }

    float inv_r[4];
#pragma unroll
    for (int r = 0; r < 4; ++r) {
        float mx = -1e30f;
#pragma unroll
        for (int kt = 0; kt < 4; ++kt)
#pragma unroll
            for (int j = 0; j < 4; ++j)
                mx = fmaxf(mx, s[kt][j][r]);
        mx = fmaxf(mx, __shfl_xor(mx, 1));
        mx = fmaxf(mx, __shfl_xor(mx, 2));
        mx = fmaxf(mx, __shfl_xor(mx, 4));
        mx = fmaxf(mx, __shfl_xor(mx, 8));
        float sum = 0.f;
#pragma unroll
        for (int kt = 0; kt < 4; ++kt)
#pragma unroll
            for (int j = 0; j < 4; ++j) {
                float pv = exp2f(s[kt][j][r] - mx);
                s[kt][j][r] = pv;
                sum += pv;
            }
        sum += __shfl_xor(sum, 1);
        sum += __shfl_xor(sum, 2);
        sum += __shfl_xor(sum, 4);
        sum += __shfl_xor(sum, 8);
        inv_r[r] = 1.f / sum;
    }

    f32x4 o[4];
#pragma unroll
    for (int j = 0; j < 4; ++j) o[j] = (f32x4){0.f, 0.f, 0.f, 0.f};

#define SPS_WRITE(VTI) do {                                          \
        _Pragma("unroll") for (int r = 0; r < 4; ++r)                \
            _Pragma("unroll") for (int j = 0; j < 4; ++j)            \
                sPs[wq0 + quad * 4 + r][j * 16 + c] = s[VTI][j][r];  \
    } while (0)

#define PV(BUF) do {                                                 \
        _Pragma("unroll") for (int ks = 0; ks < 2; ++ks) {           \
            float4 p0 = *(const float4*)&sPs[wq0 + c][ks * 32 + quad * 8]; \
            float4 p1 = *(const float4*)&sPs[wq0 + c][ks * 32 + quad * 8 + 4]; \
            f16x8 p8;                                                \
            p8[0] = (f16)p0.x; p8[1] = (f16)p0.y; p8[2] = (f16)p0.z; p8[3] = (f16)p0.w; \
            p8[4] = (f16)p1.x; p8[5] = (f16)p1.y; p8[6] = (f16)p1.z; p8[7] = (f16)p1.w; \
            __builtin_amdgcn_s_setprio(1);                           \
            _Pragma("unroll") for (int j = 0; j < 4; ++j) {          \
                f16x8 v8 = *(const f16x8*)&BUF[ks][j * 16 + c][quad * 8]; \
                o[j] = __builtin_amdgcn_mfma_f32_16x16x32_f16(p8, v8, o[j], 0, 0, 0); \
            }                                                        \
            __builtin_amdgcn_s_setprio(0);                           \
        } } while (0)

    __syncthreads();                   // VT0 + VT1 complete (softmax covered them)
    SPS_WRITE(0);
    PV(sKa);
    __syncthreads();                   // sKa reads done
    STAGE_T(sKa, &VT[vtbase + (size_t)row * VT_LD + 2 * 64 + ks * 32 + sg]);
    SPS_WRITE(1);
    PV(sKb);
    __syncthreads();                   // VT2 done; sKb reads done
    STAGE_T(sKb, &VT[vtbase + (size_t)row * VT_LD + 3 * 64 + ks * 32 + sg]);
    SPS_WRITE(2);
    PV(sKa);
    __syncthreads();                   // VT3 done
    SPS_WRITE(3);
    PV(sKb);

#pragma unroll
    for (int r = 0; r < 4; ++r) {
        int gq = q0 + wq0 + quad * 4 + r;
        if (gq >= TQ) continue;
        float inv = inv_r[r];
#pragma unroll
        for (int j = 0; j < 4; ++j) {
            size_t off = (size_t)(b * TQ + gq) * C_DIM + h * HD + j * 16 + c;
            Oh[off] = (f16)(o[j][r] * inv);
        }
    }
#undef STAGE_T
#undef QK
#undef SPS_WRITE
#undef PV
}

extern "C" void kernel_launch(void* const* d_in, const int* in_sizes, int n_in,
                              void* d_out, int out_size, void* d_ws, size_t ws_size,
                              hipStream_t stream) {
    const float* x       = (const float*)d_in[0];
    const float* conv_w  = (const float*)d_in[1];
    const float* bn_g    = (const float*)d_in[2];
    const float* bn_b    = (const float*)d_in[3];
    const float* bn_m    = (const float*)d_in[4];
    const float* bn_v    = (const float*)d_in[5];
    const float* w_q     = (const float*)d_in[6];
    const float* w_k     = (const float*)d_in[7];
    const float* w_v     = (const float*)d_in[8];
    const float* w_proj  = (const float*)d_in[9];
    const float* b_proj  = (const float*)d_in[10];
    float* out = (float*)d_out;

    const size_t QS    = (size_t)QROWS_P * 384 * sizeof(f16);
    const size_t KVS   = (size_t)KVROWS_P * 384 * sizeof(f16);
    const size_t WSZ   = 4 * (size_t)WELEM * sizeof(f16);
    const size_t VTS   = (size_t)B_SZ * 384 * VT_LD * sizeof(f16);
    const size_t WALLS = 3 * 3840 * sizeof(float);

    char* p = (char*)d_ws;
    f16* q   = (f16*)p; p += QS;
    f16* k   = (f16*)p; p += KVS;
    f16* v   = (f16*)p; p += KVS;
    f16* Wh  = (f16*)p; p += WSZ;
    f16* Wl  = (f16*)p; p += WSZ;
    f16* Qp  = (f16*)p; p += QS;
    f16* Kp  = (f16*)p; p += KVS;
    float* wAll = (float*)p; p += WALLS;

    size_t used = (size_t)(p - (char*)d_ws);
    bool sepVT = (ws_size >= used + VTS);
    f16* VT = sepVT ? (f16*)p : k;     // fallback: k region dead after qkv(Q,K)
    f16* oh = q;                       // O aliases q (q reads end in qkv)

    // 1) prep
    {
        int total = 4 * WELEM + 3 * C_DIM;
        prep_kernel<<<(total + 255) / 256, 256, 0, stream>>>(
            w_q, w_k, w_v, w_proj, conv_w, bn_g, bn_b, bn_m, bn_v, Wh, Wl, wAll);
    }

    // 2) fused conv (Q + K + V + cls), single-f16 outputs
    {
        dim3 gc(H_IN + 1, B_SZ);
        fused_conv_kernel<<<gc, 256, 0, stream>>>(x, wAll, q, k, v);
    }

    // 3) projections (swizzled 1-D grids; blocks = ceil(yMax/8)*24)
    if (sepVT) {
        int yMax = QT256 + 2 * KVT256;             // 149
        int nb = ((yMax + 7) / 8) * 24;            // 456
        qkv_proj_kernel<<<nb, 512, 0, stream>>>(q, k, v, Wh, Wl, Qp, Kp, VT, yMax);
    } else {
        int yMax = QT256 + KVT256;                 // 124
        int nb = ((yMax + 7) / 8) * 24;            // 384
        qkv_proj_kernel<<<nb, 512, 0, stream>>>(q, k, v, Wh, Wl, Qp, Kp, VT, yMax);
        int nbv = ((KVT256 + 7) / 8) * 24;         // 96
        v_proj_kernel<<<nbv, 512, 0, stream>>>(v, Wh + 2 * WELEM, Wl + 2 * WELEM, VT);
    }

    // 4) MFMA attention v7 -> oh (single f16)
    {
        dim3 ga((TQ + 63) / 64, NH, B_SZ);
        attn_mfma7<<<ga, 256, 0, stream>>>(Qp, Kp, VT, oh);
    }

    // 5) output projection + bias -> f32 out
    {
        int nb = ((QT256 + 7) / 8) * 24;           // 312
        out_proj_kernel<<<nb, 512, 0, stream>>>(oh, Wh + 3 * WELEM, Wl + 3 * WELEM,
                                                b_proj, out);
    }
}